// Round 6
// baseline (306.045 us; speedup 1.0000x reference)
//
#include <hip/hip_runtime.h>
#include <math.h>

#define DIM   1024
#define HEADS 16
#define DH    64
#define ROT   128
#define BATCH 2
#define SEQ   2048
#define ROWS  (BATCH*SEQ)        // 4096
#define PCOLS (DIM + 2*DH)       // 1152 = [q(1024) | k(64) | v(64)] per side
// 1/sqrt(128) * log2(e): scores land in log2 domain -> p = v_exp_f32(st)
#define ASC2  (0.08838834764831845f * 1.4426950408889634f)

typedef short bf16x8 __attribute__((ext_vector_type(8)));
typedef float f32x16 __attribute__((ext_vector_type(16)));

static __device__ __forceinline__ unsigned short f2bf(float f) {
    union { float f; unsigned u; } v; v.f = f;
    unsigned r = v.u + 0x7fffu + ((v.u >> 16) & 1u);   // RNE
    return (unsigned short)(r >> 16);
}
static __device__ __forceinline__ float bf2f(unsigned short u) {
    union { unsigned u; float f; } v; v.u = (unsigned)u << 16;
    return v.f;
}
static __device__ __forceinline__ int pack_bf2(float lo, float hi) {   // trunc
    union { float f; unsigned u; } a, b; a.f = lo; b.f = hi;
    return (int)((a.u >> 16) | (b.u & 0xFFFF0000u));
}

#define GL2LDS(gp, lp) __builtin_amdgcn_global_load_lds(                    \
    (const __attribute__((address_space(1))) void*)(gp),                    \
    (__attribute__((address_space(3))) void*)(lp), 16, 0, 0)

// ---------------------------------------------------------------------------
// Convert fp32 inputs -> bf16 staging buffers + rotary cos/sin table.
// ---------------------------------------------------------------------------
__global__ __launch_bounds__(256) void convert_kernel(
    const float* __restrict__ x, const float* __restrict__ a,
    const float* __restrict__ Wq_x, const float* __restrict__ Wkv_x,
    const float* __restrict__ Wq_a, const float* __restrict__ Wkv_a,
    unsigned short* __restrict__ xbf, unsigned short* __restrict__ wbf,
    float2* __restrict__ tbl)
{
    const int blk = blockIdx.x;
    const float LN1E4_64 = 0.14391156831213f;   // ln(10000)/64
    if (blk >= 2624) {                           // rotary table segment
        int local = blk - 2624;                  // 0..127
        int pos = local * 16 + (threadIdx.x >> 4);
        int i   = threadIdx.x & 15;
        #pragma unroll
        for (int j = 0; j < 4; j++) {
            int jd = i * 4 + j;
            float th = (float)pos * expf(-LN1E4_64 * (float)jd);
            float sn, cs; sincosf(th, &sn, &cs);
            tbl[pos * 64 + jd] = make_float2(cs, sn);
        }
        return;
    }
    const float* s; unsigned short* d; int seg0;
    if      (blk < 1024) { s = x;     d = xbf;           seg0 = 0;    }
    else if (blk < 2048) { s = a;     d = xbf + 4194304; seg0 = 1024; }
    else if (blk < 2304) { s = Wq_x;  d = wbf;           seg0 = 2048; }
    else if (blk < 2336) { s = Wkv_x; d = wbf + 1048576; seg0 = 2304; }
    else if (blk < 2592) { s = Wq_a;  d = wbf + 1179648; seg0 = 2336; }
    else                 { s = Wkv_a; d = wbf + 2228224; seg0 = 2592; }
    long lb = ((long)blk - seg0) * 1024;
    #pragma unroll
    for (int j = 0; j < 4; j++) {
        long idx = lb + j * 256 + threadIdx.x;
        float4 v = ((const float4*)s)[idx];
        ((ushort4*)d)[idx] = make_ushort4(f2bf(v.x), f2bf(v.y), f2bf(v.z), f2bf(v.w));
    }
}

// ---------------------------------------------------------------------------
// MFMA GEMM (bf16, 32x32x16) — unchanged from R2.
// ---------------------------------------------------------------------------
__global__ __launch_bounds__(256) void mfma_gemm_kernel(
    const unsigned short* __restrict__ xbf, const unsigned short* __restrict__ wbf,
    unsigned short* __restrict__ Pbf)
{
    const int mt = blockIdx.x, jt = blockIdx.y, side = blockIdx.z;
    const unsigned short* Ag = xbf + ((size_t)side * ROWS  + mt * 128) * DIM;
    const unsigned short* Bg = wbf + ((size_t)side * PCOLS + jt * 128) * DIM;
    unsigned short* Pp = Pbf + (size_t)side * ROWS * PCOLS;

    __shared__ __align__(16) unsigned short As[128 * 32];
    __shared__ __align__(16) unsigned short Bs[128 * 32];

    const int tid  = threadIdx.x;
    const int wave = tid >> 6, lane = tid & 63;
    const int m = lane & 31, hl = lane >> 5;
    const int wr = wave >> 1, wc = wave & 1;

    f32x16 acc[2][2];
    #pragma unroll
    for (int i2 = 0; i2 < 2; i2++)
        #pragma unroll
        for (int j2 = 0; j2 < 2; j2++) acc[i2][j2] = 0.0f;

    int sr[2], sg[2]; unsigned ldsb[2];
    #pragma unroll
    for (int it = 0; it < 2; it++) {
        int s = it * 256 + tid;
        sr[it] = s >> 2;
        sg[it] = (s & 3) ^ ((sr[it] >> 1) & 3);
        ldsb[it] = (unsigned)(it * 256 + wave * 64) * 16;
    }

    for (int k0 = 0; k0 < DIM; k0 += 32) {
        __syncthreads();
        #pragma unroll
        for (int it = 0; it < 2; it++) {
            GL2LDS(Ag + (size_t)sr[it] * DIM + k0 + sg[it] * 8, (char*)As + ldsb[it]);
            GL2LDS(Bg + (size_t)sr[it] * DIM + k0 + sg[it] * 8, (char*)Bs + ldsb[it]);
        }
        __syncthreads();
        #pragma unroll
        for (int kp = 0; kp < 2; kp++) {
            bf16x8 af[2], bff[2];
            #pragma unroll
            for (int t2 = 0; t2 < 2; t2++) {
                int ra = wr * 64 + t2 * 32 + m;
                int ga = (kp * 2 + hl) ^ ((ra >> 1) & 3);
                af[t2] = *(const bf16x8*)&As[ra * 32 + ga * 8];
                int rb = wc * 64 + t2 * 32 + m;
                int gb = (kp * 2 + hl) ^ ((rb >> 1) & 3);
                bff[t2] = *(const bf16x8*)&Bs[rb * 32 + gb * 8];
            }
            #pragma unroll
            for (int i2 = 0; i2 < 2; i2++)
                #pragma unroll
                for (int j2 = 0; j2 < 2; j2++)
                    acc[i2][j2] = __builtin_amdgcn_mfma_f32_32x32x16_bf16(
                        af[i2], bff[j2], acc[i2][j2], 0, 0, 0);
        }
    }

    const int m0 = mt * 128 + wr * 64;
    const int n0 = jt * 128 + wc * 64;
    #pragma unroll
    for (int i2 = 0; i2 < 2; i2++)
        #pragma unroll
        for (int j2 = 0; j2 < 2; j2++)
            #pragma unroll
            for (int r = 0; r < 16; r++) {
                int row = m0 + i2 * 32 + (r & 3) + 8 * (r >> 2) + 4 * hl;
                int col = n0 + j2 * 32 + m;
                Pp[(size_t)row * PCOLS + col] = f2bf(acc[i2][j2][r]);
            }
}

// ---------------------------------------------------------------------------
// Fuse v2: 16 pos per block (grid 256), all 256 threads active per phase.
//   Q: thread = (posl = tid>>5, h = (tid&31)>>1, half = tid&1): 32 d each,
//      l2norm via 1 shfl; table rotary; log2e folded into q scale.
//   K: thread = (posl, kc = tid&15, side = (tid&31)<16): 4 d each; 16-lane
//      shfl reduce per side; cross-side exchange via shfl_xor(16,32).
//   V: staged to padded LDS [128][17], written out as 16B chunks.
// ---------------------------------------------------------------------------
__global__ __launch_bounds__(256) void fuse_kernel(
    const unsigned short* __restrict__ Pbf,
    const float* __restrict__ qx_scale, const float* __restrict__ qa_scale,
    const float* __restrict__ kx_scale, const float* __restrict__ ka_scale,
    const float2* __restrict__ tbl,
    unsigned short* __restrict__ qbuf, unsigned short* __restrict__ kbuf,
    unsigned short* __restrict__ vbufT)
{
    const int base = blockIdx.x * 16;          // 16 rows per block, no b straddle
    const int b = base >> 11;
    const int tid = threadIdx.x;
    __shared__ unsigned short vsm[128][17];    // pad 17: 2-way max on store
    const int posl = tid >> 5;                 // 0..7 (pos within 8-group)
    const int c    = tid & 31;

    #pragma unroll
    for (int pp = 0; pp < 2; pp++) {
        const int row = base + pp * 8 + posl;
        const int pos = row & 2047;
        const unsigned short* Px = Pbf + (size_t)row * PCOLS;
        const unsigned short* Pa = Pbf + (size_t)ROWS * PCOLS + (size_t)row * PCOLS;
        const float2* tb = tbl + pos * 64;

        // ---------------- Q ----------------
        {
            const int h = c >> 1, half = c & 1;
            const unsigned short* qxs_p = Px + h * DH + half * 32;
            const unsigned short* qas_p = Pa + h * DH + half * 32;
            float qxv[32], qav[32];
            float ssx = 0.f, ssa = 0.f;
            #pragma unroll
            for (int g = 0; g < 8; g++) {
                ushort4 ux = ((const ushort4*)qxs_p)[g];
                ushort4 ua = ((const ushort4*)qas_p)[g];
                qxv[g*4+0]=bf2f(ux.x); qxv[g*4+1]=bf2f(ux.y); qxv[g*4+2]=bf2f(ux.z); qxv[g*4+3]=bf2f(ux.w);
                qav[g*4+0]=bf2f(ua.x); qav[g*4+1]=bf2f(ua.y); qav[g*4+2]=bf2f(ua.z); qav[g*4+3]=bf2f(ua.w);
                #pragma unroll
                for (int j = 0; j < 4; j++) {
                    ssx += qxv[g*4+j]*qxv[g*4+j];
                    ssa += qav[g*4+j]*qav[g*4+j];
                }
            }
            ssx += __shfl_xor(ssx, 1);
            ssa += __shfl_xor(ssa, 1);
            float inx = 1.0f / fmaxf(sqrtf(ssx), 1e-12f);
            float ina = 1.0f / fmaxf(sqrtf(ssa), 1e-12f);
            const float* sxp = qx_scale + h * DH + half * 32;
            const float* sap = qa_scale + h * DH + half * 32;
            unsigned short lo[32], hi[32];
            #pragma unroll
            for (int j = 0; j < 32; j++) {
                int jd = half * 32 + j;
                float qx = qxv[j] * inx * sxp[j];
                float qa = qav[j] * ina * sap[j];
                float2 cssn = tb[jd];
                lo[j] = f2bf((qx * cssn.x - qa * cssn.y) * ASC2);
                hi[j] = f2bf((qa * cssn.x + qx * cssn.y) * ASC2);
            }
            unsigned short* qp = qbuf + (((size_t)(b * HEADS + h)) * SEQ + pos) * ROT + half * 32;
            #pragma unroll
            for (int g = 0; g < 8; g++) {
                ((ushort4*)qp)[g]        = ((ushort4*)lo)[g];
                ((ushort4*)(qp + DH))[g] = ((ushort4*)hi)[g];
            }
        }
        // ---------------- K ----------------
        {
            const int kc = c & 15;
            const bool xs = (c < 16);
            const unsigned short* Pk = (xs ? Px : Pa) + DIM;
            const float* ksc = xs ? kx_scale : ka_scale;
            ushort4 ku = *(const ushort4*)(Pk + kc * 4);
            float kv[4] = {bf2f(ku.x), bf2f(ku.y), bf2f(ku.z), bf2f(ku.w)};
            float ss = kv[0]*kv[0] + kv[1]*kv[1] + kv[2]*kv[2] + kv[3]*kv[3];
            ss += __shfl_xor(ss, 1, 16);
            ss += __shfl_xor(ss, 2, 16);
            ss += __shfl_xor(ss, 4, 16);
            ss += __shfl_xor(ss, 8, 16);
            float ik = 1.0f / fmaxf(sqrtf(ss), 1e-12f);
            float sv[4], ov[4];
            #pragma unroll
            for (int j = 0; j < 4; j++) sv[j] = kv[j] * ik * ksc[kc * 4 + j];
            #pragma unroll
            for (int j = 0; j < 4; j++) ov[j] = __shfl_xor(sv[j], 16, 32);
            unsigned short ko[4];
            #pragma unroll
            for (int j = 0; j < 4; j++) {
                float2 cssn = tb[kc * 4 + j];
                float r = xs ? (sv[j] * cssn.x - ov[j] * cssn.y)
                             : (sv[j] * cssn.x + ov[j] * cssn.y);
                ko[j] = f2bf(r);
            }
            unsigned short* kp = kbuf + ((size_t)b * SEQ + pos) * ROT + (xs ? 0 : DH) + kc * 4;
            *(ushort4*)kp = make_ushort4(ko[0], ko[1], ko[2], ko[3]);
        }
        // ---------------- V -> LDS ----------------
        {
            const int kc = c & 15;
            const bool xs = (c < 16);
            const unsigned short* Pv = (xs ? Px : Pa) + DIM + DH;
            ushort4 vu = *(const ushort4*)(Pv + kc * 4);
            const int d = (xs ? 0 : DH) + kc * 4;
            const int pcol = pp * 8 + posl;
            vsm[d + 0][pcol] = vu.x; vsm[d + 1][pcol] = vu.y;
            vsm[d + 2][pcol] = vu.z; vsm[d + 3][pcol] = vu.w;
        }
    }
    __syncthreads();
    {   // vT write-out: thread -> (d = tid>>1, 8-pos half), 16B chunks
        const int d = tid >> 1, hh = tid & 1;
        unsigned short tmp[8];
        #pragma unroll
        for (int k = 0; k < 8; k++) tmp[k] = vsm[d][hh * 8 + k];
        unsigned short* vT = vbufT + (size_t)b * ROT * SEQ + (size_t)d * SEQ
                           + (base & 2047) + hh * 8;
        *(uint4*)vT = *(const uint4*)tmp;
    }
}

// ---------------------------------------------------------------------------
// MFMA flash attention: 4 waves = 2 qt x 2 ks; each wave 64 q (2 q-sets) x
// its 1024-key half. Block covers 128 q; K/V staged once per block (both ks
// regions) -> R2's 16 MB fetch regime, but LDS frag reads feed 2 MFMAs each.
// Softmax in log2 domain (log2e pre-folded): p = exp2(st), no max-tracking.
// ks halves combine unnormalized oacc/lsum via (reused) staging LDS.
// ---------------------------------------------------------------------------
__global__ __launch_bounds__(256, 2) void attn_kernel(
    const unsigned short* __restrict__ qbuf,
    const unsigned short* __restrict__ kbuf,
    const unsigned short* __restrict__ vbufT,
    float* __restrict__ out)
{
    const int qb = blockIdx.x, h = blockIdx.y, b = blockIdx.z;
    // staging: Ks[2 ks][64*128] (32KB) + Vs[2 ks][128*64] (32KB);
    // combine reuse: 2 qt * 64q * 128d fp32 (64KB) + lsum 2*2*64 (1KB)
    __shared__ __align__(16) char smem[66560];
    unsigned short* Ksb = (unsigned short*)smem;
    unsigned short* Vsb = (unsigned short*)(smem + 32768);
    const int tid  = threadIdx.x;
    const int wave = tid >> 6, lane = tid & 63;
    const int qt = wave & 1, ks = wave >> 1;
    const int m = lane & 31, hl = lane >> 5;
    const int q0 = qb * 128 + qt * 64;

    // Q resident: 2 q-sets x 8 chunks; chunk c covers d = c*16 + hl*8 + j
    bf16x8 qf[2][8];
    #pragma unroll
    for (int qs = 0; qs < 2; qs++) {
        const unsigned short* qp = qbuf +
            (((size_t)(b * HEADS + h)) * SEQ + q0 + qs * 32 + m) * ROT + hl * 8;
        #pragma unroll
        for (int c = 0; c < 8; c++) qf[qs][c] = *(const bf16x8*)(qp + c * 16);
    }

    f32x16 oacc[2][4];
    #pragma unroll
    for (int qs = 0; qs < 2; qs++)
        #pragma unroll
        for (int dt = 0; dt < 4; dt++) oacc[qs][dt] = 0.0f;
    float lsum[2] = {0.f, 0.f};

    const unsigned short* kb_ = kbuf  + (size_t)b * SEQ * ROT;
    const unsigned short* vb_ = vbufT + (size_t)b * ROT * SEQ;
    unsigned short* Ks = Ksb + ks * 8192;
    unsigned short* Vs = Vsb + ks * 8192;

    for (int t = 0; t < 16; t++) {
        __syncthreads();
        // stage tile t for ks=0 region and tile 16+t for ks=1 region
        #pragma unroll
        for (int ks2 = 0; ks2 < 2; ks2++) {
            const int kbase = (ks2 * 16 + t) * 64;
            #pragma unroll
            for (int i = 0; i < 4; i++) {
                int fg = i * 256 + tid;
                int krow = fg >> 4, kg = fg & 15;
                GL2LDS(kb_ + (size_t)(kbase + krow) * ROT + ((kg ^ (krow & 15)) << 3),
                       (char*)Ksb + ks2 * 16384 + (unsigned)(i * 256 + wave * 64) * 16);
                int rv = fg >> 3, gv = fg & 7;
                GL2LDS(vb_ + (size_t)rv * SEQ + kbase + ((gv ^ (rv & 7)) << 3),
                       (char*)Vsb + ks2 * 16384 + (unsigned)(i * 256 + wave * 64) * 16);
            }
        }
        __syncthreads();

        #pragma unroll
        for (int kg = 0; kg < 2; kg++) {
            f32x16 st0 = 0.0f, st1 = 0.0f;
            const int row = kg * 32 + m;
            #pragma unroll
            for (int c = 0; c < 8; c++) {
                bf16x8 af = *(const bf16x8*)&Ks[row * 128 + (((2 * c + hl) ^ (row & 15)) << 3)];
                st0 = __builtin_amdgcn_mfma_f32_32x32x16_bf16(af, qf[0][c], st0, 0, 0, 0);
                st1 = __builtin_amdgcn_mfma_f32_32x32x16_bf16(af, qf[1][c], st1, 0, 0, 0);
            }
            float p0[16], p1[16];
            #pragma unroll
            for (int r = 0; r < 16; r++) {
                p0[r] = __builtin_amdgcn_exp2f(st0[r]); lsum[0] += p0[r];
                p1[r] = __builtin_amdgcn_exp2f(st1[r]); lsum[1] += p1[r];
            }
            #pragma unroll
            for (int w = 0; w < 2; w++) {
                float pj0[8], pj1[8];
                #pragma unroll
                for (int tq = 0; tq < 4; tq++) {
                    float s0 = hl ? p0[8*w + tq]     : p0[8*w + 4 + tq];
                    float o0 = hl ? p0[8*w + 4 + tq] : p0[8*w + tq];
                    float r0 = __shfl_xor(s0, 32);
                    pj0[tq] = hl ? r0 : o0;  pj0[4 + tq] = hl ? o0 : r0;
                    float s1 = hl ? p1[8*w + tq]     : p1[8*w + 4 + tq];
                    float o1 = hl ? p1[8*w + 4 + tq] : p1[8*w + tq];
                    float r1 = __shfl_xor(s1, 32);
                    pj1[tq] = hl ? r1 : o1;  pj1[4 + tq] = hl ? o1 : r1;
                }
                union { int i[4]; bf16x8 v; } aP0, aP1;
                #pragma unroll
                for (int j2 = 0; j2 < 4; j2++) {
                    aP0.i[j2] = pack_bf2(pj0[2*j2], pj0[2*j2 + 1]);
                    aP1.i[j2] = pack_bf2(pj1[2*j2], pj1[2*j2 + 1]);
                }
                #pragma unroll
                for (int dt = 0; dt < 4; dt++) {
                    const int d = dt * 32 + m;
                    bf16x8 vf = *(const bf16x8*)&Vs[d * 64 +
                                    (((kg * 4 + w * 2 + hl) ^ (d & 7)) << 3)];
                    oacc[0][dt] = __builtin_amdgcn_mfma_f32_32x32x16_bf16(aP0.v, vf, oacc[0][dt], 0, 0, 0);
                    oacc[1][dt] = __builtin_amdgcn_mfma_f32_32x32x16_bf16(aP1.v, vf, oacc[1][dt], 0, 0, 0);
                }
            }
        }
    }

    // ---- combine ks halves via LDS (staging region reused) ----
    __syncthreads();
    float* cb = (float*)smem;                 // [qt][64 q][128 d]
    float* lb = (float*)(smem + 65536);       // [qt][qs][64]
    if (ks == 1) {
        #pragma unroll
        for (int qs = 0; qs < 2; qs++) {
            #pragma unroll
            for (int dt = 0; dt < 4; dt++)
                #pragma unroll
                for (int r = 0; r < 16; r++) {
                    int qrow = qs * 32 + (r & 3) + 8 * (r >> 2) + 4 * hl;
                    cb[qt * 8192 + qrow * 128 + dt * 32 + m] = oacc[qs][dt][r];
                }
            lb[qt * 128 + qs * 64 + lane] = lsum[qs];
        }
    }
    __syncthreads();
    if (ks == 0) {
        #pragma unroll
        for (int qs = 0; qs < 2; qs++) {
            float ls = lsum[qs] + lb[qt * 128 + qs * 64 + lane];
            ls += __shfl_xor(ls, 32);
            float* ob = out + ((size_t)(b * SEQ + q0 + qs * 32)) * (HEADS * ROT) + h * ROT + m;
            #pragma unroll
            for (int r = 0; r < 16; r++) {
                int qrow = (r & 3) + 8 * (r >> 2) + 4 * hl;
                float linv = 1.0f / __shfl(ls, qrow);
                float* orow = ob + (size_t)qrow * (HEADS * ROT);
                #pragma unroll
                for (int dt = 0; dt < 4; dt++) {
                    float v = oacc[qs][dt][r] +
                              cb[qt * 8192 + (qs * 32 + qrow) * 128 + dt * 32 + m];
                    orow[dt * 32] = v * linv;
                }
            }
        }
    }
}

// ---------------------------------------------------------------------------
extern "C" void kernel_launch(void* const* d_in, const int* in_sizes, int n_in,
                              void* d_out, int out_size, void* d_ws, size_t ws_size,
                              hipStream_t stream) {
    (void)in_sizes; (void)n_in; (void)out_size; (void)ws_size;
    const float* x        = (const float*)d_in[0];
    const float* a        = (const float*)d_in[1];
    const float* Wq_x     = (const float*)d_in[2];
    const float* Wkv_x    = (const float*)d_in[3];
    const float* Wq_a     = (const float*)d_in[4];
    const float* Wkv_a    = (const float*)d_in[5];
    const float* qx_scale = (const float*)d_in[6];
    const float* qa_scale = (const float*)d_in[7];
    const float* kx_scale = (const float*)d_in[8];
    const float* ka_scale = (const float*)d_in[9];
    float* out = (float*)d_out;

    unsigned short* Pbf   = (unsigned short*)d_ws;
    unsigned short* qbuf  = Pbf   + (size_t)2 * ROWS * PCOLS;
    unsigned short* kbuf  = qbuf  + (size_t)BATCH * HEADS * SEQ * ROT;
    unsigned short* vbufT = kbuf  + (size_t)BATCH * SEQ * ROT;
    unsigned short* xbf   = vbufT + (size_t)BATCH * SEQ * ROT;
    unsigned short* wbf   = xbf   + (size_t)2 * ROWS * DIM;
    float2*         tbl   = (float2*)(wbf + (size_t)2 * PCOLS * DIM);

    convert_kernel<<<dim3(2752), 256, 0, stream>>>(x, a, Wq_x, Wkv_x, Wq_a, Wkv_a,
                                                   xbf, wbf, tbl);
    mfma_gemm_kernel<<<dim3(32, 9, 2), 256, 0, stream>>>(xbf, wbf, Pbf);
    fuse_kernel<<<dim3(ROWS / 16), 256, 0, stream>>>(Pbf, qx_scale, qa_scale,
                                                     kx_scale, ka_scale, tbl,
                                                     qbuf, kbuf, vbufT);
    attn_kernel<<<dim3(SEQ / 128, HEADS, BATCH), 256, 0, stream>>>(qbuf, kbuf, vbufT, out);
}